// Round 10
// baseline (334.204 us; speedup 1.0000x reference)
//
#include <hip/hip_runtime.h>

#define D 128
#define NUSERS 100000
#define NITEMS 50000
#define NNODES 150000
#define NEDGES 3200000
#define NSEL 2048
#define NBKT 586                 // ceil(150000 / 256) row-buckets of 256 rows
#define PBLK 256                 // partition blocks
#define EPB (NEDGES / PBLK)      // 12500 edges per partition block
#define MATN (NBKT * PBLK)       // 150016 (bucket-major count matrix)
#define MB ((MATN + 255) / 256)  // 586 scan blocks
#define BCAP 8192                // LDS bucket capacity in k_p3 (records)
#define INIT_BLKS 2048
#define FLG_BLKS ((NNODES + 255) / 256)   // 586
#define SELSET_BLKS ((2 * NSEL + 255) / 256)  // 16
#define COLMASK 0x3FFFFu

typedef unsigned int uint_t;
typedef unsigned short ushort_t;

__device__ inline uint_t bf16_rne(float f) {
    uint_t x = __float_as_uint(f);
    return (x + 0x7FFFu + ((x >> 16) & 1u)) >> 16;
}

// ---- generic block exclusive scan helper ----
__device__ inline int block_excl_scan(int v, int* lds, int nw) {
    int lane = threadIdx.x & 63;
    int wid = (int)(threadIdx.x >> 6);
    int x = v;
    #pragma unroll
    for (int off = 1; off < 64; off <<= 1) {
        int y = __shfl_up(x, off);
        if (lane >= off) x += y;
    }
    if (lane == 63) lds[wid] = x;
    __syncthreads();
    if (wid == 0) {
        int s = (lane < nw) ? lds[lane] : 0;
        #pragma unroll
        for (int off = 1; off < 16; off <<= 1) {
            int y = __shfl_up(s, off);
            if (lane >= off) s += y;
        }
        if (lane < nw) lds[lane] = s;
    }
    __syncthreads();
    int waveoff = (wid == 0) ? 0 : lds[wid - 1];
    return waveoff + x - v;
}

// Fused prologue: [0,PBLK) = p1 histogram; [PBLK,+INIT_BLKS) = bf16 table init;
// rest = zero flags + selflag. All independent.
__global__ void k_prologue(const int* __restrict__ row, int* __restrict__ mat,
                           const float4* __restrict__ u4, const float4* __restrict__ i4,
                           uint4* __restrict__ cur,
                           int* __restrict__ flags, int* __restrict__ selflag) {
    __shared__ int h[NBKT];
    int blk = blockIdx.x;
    if (blk < PBLK) {
        for (int i = threadIdx.x; i < NBKT; i += 256) h[i] = 0;
        __syncthreads();
        int beg = blk * EPB, end = beg + EPB;
        for (int e = beg + threadIdx.x; e < end; e += 256)
            atomicAdd(&h[row[e] >> 8], 1);
        __syncthreads();
        for (int i = threadIdx.x; i < NBKT; i += 256)
            mat[i * PBLK + blk] = h[i];
    } else if (blk < PBLK + INIT_BLKS) {
        size_t total8 = (size_t)NNODES * D / 8;
        size_t ub8 = (size_t)NUSERS * D / 8;
        size_t stride = (size_t)INIT_BLKS * 256;
        for (size_t i = (size_t)(blk - PBLK) * 256 + threadIdx.x; i < total8; i += stride) {
            const float4* src = (i < ub8) ? &u4[2 * i] : &i4[2 * (i - ub8)];
            float4 a = src[0], b = src[1];
            uint4 o;
            o.x = (bf16_rne(a.y) << 16) | bf16_rne(a.x);
            o.y = (bf16_rne(a.w) << 16) | bf16_rne(a.z);
            o.z = (bf16_rne(b.y) << 16) | bf16_rne(b.x);
            o.w = (bf16_rne(b.w) << 16) | bf16_rne(b.z);
            cur[i] = o;
        }
    } else {
        int i = (blk - PBLK - INIT_BLKS) * 256 + threadIdx.x;
        if (i < NNODES) { flags[i] = 0; selflag[i] = 0; }
    }
}

__global__ void k_blocksum(const int* __restrict__ src, int* __restrict__ bsums, int n) {
    int i = blockIdx.x * 256 + threadIdx.x;
    int v = (i < n) ? src[i] : 0;
    #pragma unroll
    for (int off = 32; off; off >>= 1) v += __shfl_down(v, off);
    __shared__ int lds[4];
    int lane = threadIdx.x & 63, wid = (int)(threadIdx.x >> 6);
    if (lane == 0) lds[wid] = v;
    __syncthreads();
    if (threadIdx.x == 0) bsums[blockIdx.x] = lds[0] + lds[1] + lds[2] + lds[3];
}

// merged scan (+ extra blocks set selflag/flags for selected nodes)
__global__ void k_scan2(int* __restrict__ mat, const int* __restrict__ bsums, int n,
                        const int* __restrict__ users, const int* __restrict__ items,
                        int* __restrict__ selflag, int* __restrict__ flags) {
    int b = blockIdx.x;
    if (b >= MB) {
        int idx = (b - MB) * 256 + threadIdx.x;
        if (idx < 2 * NSEL) {
            int node = (idx < NSEL) ? users[idx] : NUSERS + items[idx - NSEL];
            selflag[node] = 1;
            flags[node] = 1;
        }
        return;
    }
    __shared__ int red[4];
    __shared__ int lds[4];
    int lane = threadIdx.x & 63, wid = (int)(threadIdx.x >> 6);
    int s = 0;
    for (int j = threadIdx.x; j < b; j += 256) s += bsums[j];
    #pragma unroll
    for (int off = 32; off; off >>= 1) s += __shfl_down(s, off);
    if (lane == 0) red[wid] = s;
    __syncthreads();
    int base = red[0] + red[1] + red[2] + red[3];
    int i = b * 256 + threadIdx.x;
    int v = (i < n) ? mat[i] : 0;
    int ex = block_excl_scan(v, lds, 4);
    if (i < n) mat[i] = base + ex;
}

// P2: partition scatter; t4 = (rowInBucket<<18)|col (26 bits), tv = val q14
__global__ void k_p2(const int* __restrict__ row, const int* __restrict__ col,
                     const float* __restrict__ val, const int* __restrict__ mat,
                     uint_t* __restrict__ t4, ushort_t* __restrict__ tv) {
    __shared__ int cur[NBKT];
    for (int i = threadIdx.x; i < NBKT; i += 256)
        cur[i] = mat[i * PBLK + blockIdx.x];
    __syncthreads();
    int beg = blockIdx.x * EPB, end = beg + EPB;
    for (int e = beg + threadIdx.x; e < end; e += 256) {
        int r = row[e];
        int b = r >> 8;
        int pos = atomicAdd(&cur[b], 1);
        int q = (int)(val[e] * 16384.f + 0.5f);
        if (q > 16383) q = 16383;
        t4[pos] = ((uint_t)(r & 255) << 18) | (uint_t)col[e];
        tv[pos] = (ushort_t)q;
    }
}

// P3: per-bucket exact CSR via LDS staging; writes packed 4B recs (val14|col18)
// + fused mark: for records of selected rows, set flags[col]=1
__global__ void k_p3(const uint_t* __restrict__ t4, const ushort_t* __restrict__ tv,
                     const int* __restrict__ mat, uint_t* __restrict__ recs,
                     int* __restrict__ row_start,
                     const int* __restrict__ selflag, int* __restrict__ flags) {
    __shared__ uint_t b4[BCAP];       // 32 KB
    __shared__ ushort_t bv[BCAP];     // 16 KB
    __shared__ int h[256];
    __shared__ int lds[4];
    __shared__ unsigned char selb[256];
    int b = blockIdx.x;
    int beg = mat[b * PBLK];
    int end = (b + 1 < NBKT) ? mat[(b + 1) * PBLK] : NEDGES;
    int n = end - beg;
    int rowid = b * 256 + threadIdx.x;
    h[threadIdx.x] = 0;
    selb[threadIdx.x] = (rowid < NNODES) ? (unsigned char)selflag[rowid] : 0;
    if (n <= BCAP) {
        for (int i = threadIdx.x; i < n; i += 256) { b4[i] = t4[beg + i]; bv[i] = tv[beg + i]; }
        __syncthreads();
        for (int i = threadIdx.x; i < n; i += 256)
            atomicAdd(&h[b4[i] >> 18], 1);
        __syncthreads();
        int ex = block_excl_scan(h[threadIdx.x], lds, 4);
        if (rowid < NNODES) row_start[rowid] = beg + ex;
        if (b == NBKT - 1 && threadIdx.x == 0) row_start[NNODES] = NEDGES;
        h[threadIdx.x] = ex;
        __syncthreads();
        for (int i = threadIdx.x; i < n; i += 256) {
            uint_t a = b4[i];
            int r = (int)(a >> 18);
            uint_t c = a & COLMASK;
            int pos = beg + atomicAdd(&h[r], 1);
            recs[pos] = ((uint_t)bv[i] << 18) | c;
            if (selb[r]) flags[c] = 1;
        }
    } else {
        __syncthreads();
        for (int e = beg + threadIdx.x; e < end; e += 256)
            atomicAdd(&h[t4[e] >> 18], 1);
        __syncthreads();
        int ex = block_excl_scan(h[threadIdx.x], lds, 4);
        if (rowid < NNODES) row_start[rowid] = beg + ex;
        if (b == NBKT - 1 && threadIdx.x == 0) row_start[NNODES] = NEDGES;
        h[threadIdx.x] = ex;
        __syncthreads();
        for (int e = beg + threadIdx.x; e < end; e += 256) {
            uint_t a = t4[e];
            int r = (int)(a >> 18);
            uint_t c = a & COLMASK;
            int pos = beg + atomicAdd(&h[r], 1);
            recs[pos] = ((uint_t)tv[e] << 18) | c;
            if (selb[r]) flags[c] = 1;
        }
    }
}

// CSR SpMM on bf16 table: one wave per row, register accumulation, single
// non-atomic write. use_flags: skip rows whose output is never consumed.
__global__ void k_spmm_csr(const uint_t* __restrict__ emb, uint_t* __restrict__ outp,
                           const int* __restrict__ row_start,
                           const uint_t* __restrict__ recs,
                           const int* __restrict__ flags, int use_flags) {
    int lane = threadIdx.x & 63;
    int w = (int)((blockIdx.x * blockDim.x + threadIdx.x) >> 6);
    if (w >= NNODES) return;
    if (use_flags && __builtin_amdgcn_readfirstlane(flags[w]) == 0) return;
    int beg = __builtin_amdgcn_readfirstlane(row_start[w]);
    int end = __builtin_amdgcn_readfirstlane(row_start[w + 1]);
    float ax = 0.f, ay = 0.f;
    int e = beg;
    for (; e + 3 < end; e += 4) {
        uint_t q0 = recs[e], q1 = recs[e + 1], q2 = recs[e + 2], q3 = recs[e + 3];
        uint_t g0 = emb[(size_t)(q0 & COLMASK) * 64 + lane];
        uint_t g1 = emb[(size_t)(q1 & COLMASK) * 64 + lane];
        uint_t g2 = emb[(size_t)(q2 & COLMASK) * 64 + lane];
        uint_t g3 = emb[(size_t)(q3 & COLMASK) * 64 + lane];
        float v0 = (float)(q0 >> 18) * (1.f / 16384.f);
        float v1 = (float)(q1 >> 18) * (1.f / 16384.f);
        float v2 = (float)(q2 >> 18) * (1.f / 16384.f);
        float v3 = (float)(q3 >> 18) * (1.f / 16384.f);
        ax += v0 * __uint_as_float(g0 << 16) + v1 * __uint_as_float(g1 << 16)
            + v2 * __uint_as_float(g2 << 16) + v3 * __uint_as_float(g3 << 16);
        ay += v0 * __uint_as_float(g0 & 0xFFFF0000u) + v1 * __uint_as_float(g1 & 0xFFFF0000u)
            + v2 * __uint_as_float(g2 & 0xFFFF0000u) + v3 * __uint_as_float(g3 & 0xFFFF0000u);
    }
    for (; e < end; ++e) {
        uint_t q = recs[e];
        float v = (float)(q >> 18) * (1.f / 16384.f);
        uint_t g = emb[(size_t)(q & COLMASK) * 64 + lane];
        ax += v * __uint_as_float(g << 16);
        ay += v * __uint_as_float(g & 0xFFFF0000u);
    }
    outp[(size_t)w * 64 + lane] = (bf16_rne(ay) << 16) | bf16_rne(ax);
}

// Final fused kernel: per selected slot compute e0+e1+e2+l3, then paired dot.
// Block b: waves 0,1 = user slots 2b,2b+1; waves 2,3 = item slots 2b,2b+1.
__global__ void k_final(const uint_t* __restrict__ embA,      // e2 table (bufA)
                        const uint_t* __restrict__ embB,      // e1 table (bufB)
                        const float* __restrict__ user_emb,
                        const float* __restrict__ item_emb,
                        const int* __restrict__ users, const int* __restrict__ items,
                        const int* __restrict__ row_start, const uint_t* __restrict__ recs,
                        float* __restrict__ out) {
    __shared__ float ush[2][64][2];
    int lane = threadIdx.x & 63;
    int wid = (int)(threadIdx.x >> 6);        // 0..3
    int pairIdx = blockIdx.x * 2 + (wid & 1); // output index
    int isItem = wid >> 1;
    int node, idx0;
    const float* e0p;
    if (isItem) {
        idx0 = items[pairIdx];
        node = NUSERS + idx0;
        e0p = &item_emb[(size_t)idx0 * D];
    } else {
        idx0 = users[pairIdx];
        node = idx0;
        e0p = &user_emb[(size_t)idx0 * D];
    }
    const float2 e0 = *(const float2*)(&e0p[lane * 2]);
    uint_t u1 = embB[(size_t)node * 64 + lane];
    uint_t u2 = embA[(size_t)node * 64 + lane];
    float ax = e0.x + __uint_as_float(u1 << 16) + __uint_as_float(u2 << 16);
    float ay = e0.y + __uint_as_float(u1 & 0xFFFF0000u) + __uint_as_float(u2 & 0xFFFF0000u);
    int beg = __builtin_amdgcn_readfirstlane(row_start[node]);
    int end = __builtin_amdgcn_readfirstlane(row_start[node + 1]);
    for (int e = beg; e < end; ++e) {
        uint_t q = recs[e];
        float v = (float)(q >> 18) * (1.f / 16384.f);
        uint_t g = embA[(size_t)(q & COLMASK) * 64 + lane];
        ax += v * __uint_as_float(g << 16);
        ay += v * __uint_as_float(g & 0xFFFF0000u);
    }
    if (!isItem) { ush[wid][lane][0] = ax; ush[wid][lane][1] = ay; }
    __syncthreads();
    if (isItem) {
        float s = ush[wid - 2][lane][0] * ax + ush[wid - 2][lane][1] * ay;
        #pragma unroll
        for (int off = 32; off; off >>= 1) s += __shfl_down(s, off);
        if (lane == 0) out[pairIdx] = s * (1.0f / 16.0f);
    }
}

extern "C" void kernel_launch(void* const* d_in, const int* in_sizes, int n_in,
                              void* d_out, int out_size, void* d_ws, size_t ws_size,
                              hipStream_t stream) {
    const float* user_emb = (const float*)d_in[0];
    const float* item_emb = (const float*)d_in[1];
    const float* edge_val = (const float*)d_in[2];
    const int*   edge_row = (const int*)d_in[3];
    const int*   edge_col = (const int*)d_in[4];
    const int*   users    = (const int*)d_in[5];
    const int*   items    = (const int*)d_in[6];
    float* out = (float*)d_out;

    const size_t tab = (size_t)NNODES * D;                   // elements
    ushort_t* bufA   = (ushort_t*)d_ws;                      // 38.4 MB bf16
    ushort_t* bufB   = bufA + tab;                           // 38.4 MB bf16
    uint_t* recs     = (uint_t*)(bufB + tab);                // 12.8 MB packed
    uint_t* t4       = recs + NEDGES;                        // 12.8 MB
    ushort_t* tv     = (ushort_t*)(t4 + NEDGES);             // 6.4 MB
    int*   mat       = (int*)(tv + NEDGES);                  // 600 KB
    int*   row_start = mat + MATN;                           // 600 KB
    int*   flags     = row_start + NNODES + 1;               // 600 KB
    int*   selflag   = flags + NNODES;                       // 600 KB
    int*   bsums     = selflag + NNODES;                     // 2.4 KB

    // ---- prologue: p1 histogram + bf16 init + zero flags/selflag ----
    k_prologue<<<PBLK + INIT_BLKS + FLG_BLKS, 256, 0, stream>>>(
        edge_row, mat, (const float4*)user_emb, (const float4*)item_emb,
        (uint4*)bufA, flags, selflag);

    // ---- CSR build ----
    k_blocksum<<<MB, 256, 0, stream>>>(mat, bsums, MATN);
    k_scan2<<<MB + SELSET_BLKS, 256, 0, stream>>>(mat, bsums, MATN,
                                                  users, items, selflag, flags);
    k_p2<<<PBLK, 256, 0, stream>>>(edge_row, edge_col, edge_val, mat, t4, tv);
    k_p3<<<NBKT, 256, 0, stream>>>(t4, tv, mat, recs, row_start, selflag, flags);

    // layer 1: full
    k_spmm_csr<<<(NNODES + 3) / 4, 256, 0, stream>>>((const uint_t*)bufA, (uint_t*)bufB,
                                                     row_start, recs, flags, 0);
    // layer 2: only rows consumed downstream (~47%)
    k_spmm_csr<<<(NNODES + 3) / 4, 256, 0, stream>>>((const uint_t*)bufB, (uint_t*)bufA,
                                                     row_start, recs, flags, 1);
    // final: e0+e1+e2+layer3 at selected slots + paired dot
    k_final<<<NSEL / 2, 256, 0, stream>>>((const uint_t*)bufA, (const uint_t*)bufB,
                                          user_emb, item_emb, users, items,
                                          row_start, recs, out);
}

// Round 11
// 305.373 us; speedup vs baseline: 1.0944x; 1.0944x over previous
//
#include <hip/hip_runtime.h>

#define D 128
#define NUSERS 100000
#define NITEMS 50000
#define NNODES 150000
#define NEDGES 3200000
#define NSEL 2048
#define NBKT 586                 // ceil(150000 / 256) row-buckets of 256 rows
#define PBLK 1024                // partition blocks (4/CU -> 4 waves/SIMD)
#define EPB (NEDGES / PBLK)      // 3125 edges per partition block
#define MATN (NBKT * PBLK)       // 600064 (bucket-major count matrix)
#define MB (MATN / 256)          // 2344 scan blocks
#define BCAP 8192                // LDS bucket capacity in k_p3 (records)
#define INIT_BLKS 2048
#define FLG_BLKS ((NNODES + 255) / 256)   // 586
#define SELSET_BLKS ((2 * NSEL + 255) / 256)  // 16
#define COLMASK 0x3FFFFu

typedef unsigned int uint_t;
typedef unsigned short ushort_t;

__device__ inline uint_t bf16_rne(float f) {
    uint_t x = __float_as_uint(f);
    return (x + 0x7FFFu + ((x >> 16) & 1u)) >> 16;
}

// ---- generic block exclusive scan helper ----
__device__ inline int block_excl_scan(int v, int* lds, int nw) {
    int lane = threadIdx.x & 63;
    int wid = (int)(threadIdx.x >> 6);
    int x = v;
    #pragma unroll
    for (int off = 1; off < 64; off <<= 1) {
        int y = __shfl_up(x, off);
        if (lane >= off) x += y;
    }
    if (lane == 63) lds[wid] = x;
    __syncthreads();
    if (wid == 0) {
        int s = (lane < nw) ? lds[lane] : 0;
        #pragma unroll
        for (int off = 1; off < 16; off <<= 1) {
            int y = __shfl_up(s, off);
            if (lane >= off) s += y;
        }
        if (lane < nw) lds[lane] = s;
    }
    __syncthreads();
    int waveoff = (wid == 0) ? 0 : lds[wid - 1];
    return waveoff + x - v;
}

// Fused prologue: [0,PBLK) = p1 histogram; [PBLK,+INIT_BLKS) = bf16 table init;
// rest = zero flags + selflag. All independent.
__global__ void k_prologue(const int* __restrict__ row, int* __restrict__ mat,
                           const float4* __restrict__ u4, const float4* __restrict__ i4,
                           uint4* __restrict__ cur,
                           int* __restrict__ flags, int* __restrict__ selflag) {
    __shared__ int h[NBKT];
    int blk = blockIdx.x;
    if (blk < PBLK) {
        for (int i = threadIdx.x; i < NBKT; i += 256) h[i] = 0;
        __syncthreads();
        int beg = blk * EPB, end = beg + EPB;
        for (int e = beg + threadIdx.x; e < end; e += 256)
            atomicAdd(&h[row[e] >> 8], 1);
        __syncthreads();
        for (int i = threadIdx.x; i < NBKT; i += 256)
            mat[i * PBLK + blk] = h[i];
    } else if (blk < PBLK + INIT_BLKS) {
        size_t total8 = (size_t)NNODES * D / 8;
        size_t ub8 = (size_t)NUSERS * D / 8;
        size_t stride = (size_t)INIT_BLKS * 256;
        for (size_t i = (size_t)(blk - PBLK) * 256 + threadIdx.x; i < total8; i += stride) {
            const float4* src = (i < ub8) ? &u4[2 * i] : &i4[2 * (i - ub8)];
            float4 a = src[0], b = src[1];
            uint4 o;
            o.x = (bf16_rne(a.y) << 16) | bf16_rne(a.x);
            o.y = (bf16_rne(a.w) << 16) | bf16_rne(a.z);
            o.z = (bf16_rne(b.y) << 16) | bf16_rne(b.x);
            o.w = (bf16_rne(b.w) << 16) | bf16_rne(b.z);
            cur[i] = o;
        }
    } else {
        int i = (blk - PBLK - INIT_BLKS) * 256 + threadIdx.x;
        if (i < NNODES) { flags[i] = 0; selflag[i] = 0; }
    }
}

__global__ void k_blocksum(const int* __restrict__ src, int* __restrict__ bsums, int n) {
    int i = blockIdx.x * 256 + threadIdx.x;
    int v = (i < n) ? src[i] : 0;
    #pragma unroll
    for (int off = 32; off; off >>= 1) v += __shfl_down(v, off);
    __shared__ int lds[4];
    int lane = threadIdx.x & 63, wid = (int)(threadIdx.x >> 6);
    if (lane == 0) lds[wid] = v;
    __syncthreads();
    if (threadIdx.x == 0) bsums[blockIdx.x] = lds[0] + lds[1] + lds[2] + lds[3];
}

// merged scan (+ extra blocks set selflag/flags for selected nodes)
__global__ void k_scan2(int* __restrict__ mat, const int* __restrict__ bsums, int n,
                        const int* __restrict__ users, const int* __restrict__ items,
                        int* __restrict__ selflag, int* __restrict__ flags) {
    int b = blockIdx.x;
    if (b >= MB) {
        int idx = (b - MB) * 256 + threadIdx.x;
        if (idx < 2 * NSEL) {
            int node = (idx < NSEL) ? users[idx] : NUSERS + items[idx - NSEL];
            selflag[node] = 1;
            flags[node] = 1;
        }
        return;
    }
    __shared__ int red[4];
    __shared__ int lds[4];
    int lane = threadIdx.x & 63, wid = (int)(threadIdx.x >> 6);
    int s = 0;
    for (int j = threadIdx.x; j < b; j += 256) s += bsums[j];
    #pragma unroll
    for (int off = 32; off; off >>= 1) s += __shfl_down(s, off);
    if (lane == 0) red[wid] = s;
    __syncthreads();
    int base = red[0] + red[1] + red[2] + red[3];
    int i = b * 256 + threadIdx.x;
    int v = (i < n) ? mat[i] : 0;
    int ex = block_excl_scan(v, lds, 4);
    if (i < n) mat[i] = base + ex;
}

// P2: partition scatter; tmp.x = row-in-bucket, tmp.y = packed (val14<<18)|col18.
// Single 8B store per edge.
__global__ void k_p2(const int* __restrict__ row, const int* __restrict__ col,
                     const float* __restrict__ val, const int* __restrict__ mat,
                     int2* __restrict__ tmp) {
    __shared__ int cur[NBKT];
    for (int i = threadIdx.x; i < NBKT; i += 256)
        cur[i] = mat[i * PBLK + blockIdx.x];
    __syncthreads();
    int beg = blockIdx.x * EPB, end = beg + EPB;
    for (int e = beg + threadIdx.x; e < end; e += 256) {
        int r = row[e];
        int b = r >> 8;
        int pos = atomicAdd(&cur[b], 1);
        int q = (int)(val[e] * 16384.f + 0.5f);
        if (q > 16383) q = 16383;
        int2 rc;
        rc.x = r & 255;
        rc.y = (int)(((uint_t)q << 18) | (uint_t)col[e]);
        tmp[pos] = rc;
    }
}

// P3: per-bucket exact CSR via LDS staging; writes packed 4B recs (val14|col18)
// + fused mark: for records of selected rows, set flags[col]=1
__global__ void k_p3(const int2* __restrict__ tmp, const int* __restrict__ mat,
                     uint_t* __restrict__ recs, int* __restrict__ row_start,
                     const int* __restrict__ selflag, int* __restrict__ flags) {
    __shared__ int2 buf[BCAP];        // 64 KB
    __shared__ int h[256];
    __shared__ int lds[4];
    __shared__ unsigned char selb[256];
    int b = blockIdx.x;
    int beg = mat[b * PBLK];
    int end = (b + 1 < NBKT) ? mat[(b + 1) * PBLK] : NEDGES;
    int n = end - beg;
    int rowid = b * 256 + threadIdx.x;
    h[threadIdx.x] = 0;
    selb[threadIdx.x] = (rowid < NNODES) ? (unsigned char)selflag[rowid] : 0;
    if (n <= BCAP) {
        for (int i = threadIdx.x; i < n; i += 256) buf[i] = tmp[beg + i];
        __syncthreads();
        for (int i = threadIdx.x; i < n; i += 256)
            atomicAdd(&h[buf[i].x], 1);
        __syncthreads();
        int ex = block_excl_scan(h[threadIdx.x], lds, 4);
        if (rowid < NNODES) row_start[rowid] = beg + ex;
        if (b == NBKT - 1 && threadIdx.x == 0) row_start[NNODES] = NEDGES;
        h[threadIdx.x] = ex;
        __syncthreads();
        for (int i = threadIdx.x; i < n; i += 256) {
            int2 rc = buf[i];
            int r = rc.x;
            int pos = beg + atomicAdd(&h[r], 1);
            recs[pos] = (uint_t)rc.y;
            if (selb[r]) flags[(uint_t)rc.y & COLMASK] = 1;
        }
    } else {
        __syncthreads();
        for (int e = beg + threadIdx.x; e < end; e += 256)
            atomicAdd(&h[tmp[e].x], 1);
        __syncthreads();
        int ex = block_excl_scan(h[threadIdx.x], lds, 4);
        if (rowid < NNODES) row_start[rowid] = beg + ex;
        if (b == NBKT - 1 && threadIdx.x == 0) row_start[NNODES] = NEDGES;
        h[threadIdx.x] = ex;
        __syncthreads();
        for (int e = beg + threadIdx.x; e < end; e += 256) {
            int2 rc = tmp[e];
            int r = rc.x;
            int pos = beg + atomicAdd(&h[r], 1);
            recs[pos] = (uint_t)rc.y;
            if (selb[r]) flags[(uint_t)rc.y & COLMASK] = 1;
        }
    }
}

// CSR SpMM on bf16 table: one wave per row, register accumulation, single
// non-atomic write. use_flags: skip rows whose output is never consumed.
__global__ void k_spmm_csr(const uint_t* __restrict__ emb, uint_t* __restrict__ outp,
                           const int* __restrict__ row_start,
                           const uint_t* __restrict__ recs,
                           const int* __restrict__ flags, int use_flags) {
    int lane = threadIdx.x & 63;
    int w = (int)((blockIdx.x * blockDim.x + threadIdx.x) >> 6);
    if (w >= NNODES) return;
    if (use_flags && __builtin_amdgcn_readfirstlane(flags[w]) == 0) return;
    int beg = __builtin_amdgcn_readfirstlane(row_start[w]);
    int end = __builtin_amdgcn_readfirstlane(row_start[w + 1]);
    float ax = 0.f, ay = 0.f;
    int e = beg;
    for (; e + 3 < end; e += 4) {
        uint_t q0 = recs[e], q1 = recs[e + 1], q2 = recs[e + 2], q3 = recs[e + 3];
        uint_t g0 = emb[(size_t)(q0 & COLMASK) * 64 + lane];
        uint_t g1 = emb[(size_t)(q1 & COLMASK) * 64 + lane];
        uint_t g2 = emb[(size_t)(q2 & COLMASK) * 64 + lane];
        uint_t g3 = emb[(size_t)(q3 & COLMASK) * 64 + lane];
        float v0 = (float)(q0 >> 18) * (1.f / 16384.f);
        float v1 = (float)(q1 >> 18) * (1.f / 16384.f);
        float v2 = (float)(q2 >> 18) * (1.f / 16384.f);
        float v3 = (float)(q3 >> 18) * (1.f / 16384.f);
        ax += v0 * __uint_as_float(g0 << 16) + v1 * __uint_as_float(g1 << 16)
            + v2 * __uint_as_float(g2 << 16) + v3 * __uint_as_float(g3 << 16);
        ay += v0 * __uint_as_float(g0 & 0xFFFF0000u) + v1 * __uint_as_float(g1 & 0xFFFF0000u)
            + v2 * __uint_as_float(g2 & 0xFFFF0000u) + v3 * __uint_as_float(g3 & 0xFFFF0000u);
    }
    for (; e < end; ++e) {
        uint_t q = recs[e];
        float v = (float)(q >> 18) * (1.f / 16384.f);
        uint_t g = emb[(size_t)(q & COLMASK) * 64 + lane];
        ax += v * __uint_as_float(g << 16);
        ay += v * __uint_as_float(g & 0xFFFF0000u);
    }
    outp[(size_t)w * 64 + lane] = (bf16_rne(ay) << 16) | bf16_rne(ax);
}

// Final fused kernel: per selected slot compute e0+e1+e2+l3, then paired dot.
// Block b: waves 0,1 = user slots 2b,2b+1; waves 2,3 = item slots 2b,2b+1.
__global__ void k_final(const uint_t* __restrict__ embA,      // e2 table (bufA)
                        const uint_t* __restrict__ embB,      // e1 table (bufB)
                        const float* __restrict__ user_emb,
                        const float* __restrict__ item_emb,
                        const int* __restrict__ users, const int* __restrict__ items,
                        const int* __restrict__ row_start, const uint_t* __restrict__ recs,
                        float* __restrict__ out) {
    __shared__ float ush[2][64][2];
    int lane = threadIdx.x & 63;
    int wid = (int)(threadIdx.x >> 6);        // 0..3
    int pairIdx = blockIdx.x * 2 + (wid & 1); // output index
    int isItem = wid >> 1;
    int node, idx0;
    const float* e0p;
    if (isItem) {
        idx0 = items[pairIdx];
        node = NUSERS + idx0;
        e0p = &item_emb[(size_t)idx0 * D];
    } else {
        idx0 = users[pairIdx];
        node = idx0;
        e0p = &user_emb[(size_t)idx0 * D];
    }
    const float2 e0 = *(const float2*)(&e0p[lane * 2]);
    uint_t u1 = embB[(size_t)node * 64 + lane];
    uint_t u2 = embA[(size_t)node * 64 + lane];
    float ax = e0.x + __uint_as_float(u1 << 16) + __uint_as_float(u2 << 16);
    float ay = e0.y + __uint_as_float(u1 & 0xFFFF0000u) + __uint_as_float(u2 & 0xFFFF0000u);
    int beg = __builtin_amdgcn_readfirstlane(row_start[node]);
    int end = __builtin_amdgcn_readfirstlane(row_start[node + 1]);
    for (int e = beg; e < end; ++e) {
        uint_t q = recs[e];
        float v = (float)(q >> 18) * (1.f / 16384.f);
        uint_t g = embA[(size_t)(q & COLMASK) * 64 + lane];
        ax += v * __uint_as_float(g << 16);
        ay += v * __uint_as_float(g & 0xFFFF0000u);
    }
    if (!isItem) { ush[wid][lane][0] = ax; ush[wid][lane][1] = ay; }
    __syncthreads();
    if (isItem) {
        float s = ush[wid - 2][lane][0] * ax + ush[wid - 2][lane][1] * ay;
        #pragma unroll
        for (int off = 32; off; off >>= 1) s += __shfl_down(s, off);
        if (lane == 0) out[pairIdx] = s * (1.0f / 16.0f);
    }
}

extern "C" void kernel_launch(void* const* d_in, const int* in_sizes, int n_in,
                              void* d_out, int out_size, void* d_ws, size_t ws_size,
                              hipStream_t stream) {
    const float* user_emb = (const float*)d_in[0];
    const float* item_emb = (const float*)d_in[1];
    const float* edge_val = (const float*)d_in[2];
    const int*   edge_row = (const int*)d_in[3];
    const int*   edge_col = (const int*)d_in[4];
    const int*   users    = (const int*)d_in[5];
    const int*   items    = (const int*)d_in[6];
    float* out = (float*)d_out;

    const size_t tab = (size_t)NNODES * D;                   // elements
    ushort_t* bufA   = (ushort_t*)d_ws;                      // 38.4 MB bf16
    ushort_t* bufB   = bufA + tab;                           // 38.4 MB bf16
    uint_t* recs     = (uint_t*)(bufB + tab);                // 12.8 MB packed
    int2*  tmp       = (int2*)(recs + NEDGES);               // 25.6 MB
    int*   mat       = (int*)(tmp + NEDGES);                 // 2.4 MB
    int*   row_start = mat + MATN;                           // 600 KB
    int*   flags     = row_start + NNODES + 1;               // 600 KB
    int*   selflag   = flags + NNODES;                       // 600 KB
    int*   bsums     = selflag + NNODES;                     // 9.4 KB

    // ---- prologue: p1 histogram + bf16 init + zero flags/selflag ----
    k_prologue<<<PBLK + INIT_BLKS + FLG_BLKS, 256, 0, stream>>>(
        edge_row, mat, (const float4*)user_emb, (const float4*)item_emb,
        (uint4*)bufA, flags, selflag);

    // ---- CSR build ----
    k_blocksum<<<MB, 256, 0, stream>>>(mat, bsums, MATN);
    k_scan2<<<MB + SELSET_BLKS, 256, 0, stream>>>(mat, bsums, MATN,
                                                  users, items, selflag, flags);
    k_p2<<<PBLK, 256, 0, stream>>>(edge_row, edge_col, edge_val, mat, tmp);
    k_p3<<<NBKT, 256, 0, stream>>>(tmp, mat, recs, row_start, selflag, flags);

    // layer 1: full
    k_spmm_csr<<<(NNODES + 3) / 4, 256, 0, stream>>>((const uint_t*)bufA, (uint_t*)bufB,
                                                     row_start, recs, flags, 0);
    // layer 2: only rows consumed downstream (~47%)
    k_spmm_csr<<<(NNODES + 3) / 4, 256, 0, stream>>>((const uint_t*)bufB, (uint_t*)bufA,
                                                     row_start, recs, flags, 1);
    // final: e0+e1+e2+layer3 at selected slots + paired dot
    k_final<<<NSEL / 2, 256, 0, stream>>>((const uint_t*)bufA, (const uint_t*)bufB,
                                          user_emb, item_emb, users, items,
                                          row_start, recs, out);
}

// Round 12
// 283.361 us; speedup vs baseline: 1.1794x; 1.0777x over previous
//
#include <hip/hip_runtime.h>

#define D 128
#define NUSERS 100000
#define NITEMS 50000
#define NNODES 150000
#define NEDGES 3200000
#define NSEL 2048
#define NBKT 586                 // ceil(150000 / 256) row-buckets of 256 rows
#define PBLK 1024                // partition blocks (4/CU -> 4 waves/SIMD)
#define EPB (NEDGES / PBLK)      // 3125 edges per partition block
#define MATN (NBKT * PBLK)       // 600064 (bucket-major count matrix)
#define MB (MATN / 256)          // 2344 scan blocks
#define BCAP 8192                // LDS bucket capacity in k_p3 (records)
#define INIT_BLKS 2048
#define FLG_BLKS ((NNODES + 255) / 256)   // 586
#define SELSET_BLKS ((2 * NSEL + 255) / 256)  // 16
#define COLMASK 0x3FFFFu

typedef unsigned int uint_t;
typedef unsigned short ushort_t;

__device__ inline uint_t bf16_rne(float f) {
    uint_t x = __float_as_uint(f);
    return (x + 0x7FFFu + ((x >> 16) & 1u)) >> 16;
}

// same-XCD-adjacent column permutation for mat/tmp segments (PBLK=1024, 8 XCDs)
__device__ inline int mcol(int b) { return ((b & 7) << 7) | (b >> 3); }

// bijective XCD-chunked block swizzle (m204 variant; works for any n)
__device__ inline int swz_blk(int b, int n) {
    int q = n >> 3, r = n & 7;
    int x = b & 7, i = b >> 3;
    return (x < r) ? x * (q + 1) + i : r * (q + 1) + (x - r) * q + i;
}

// ---- generic block exclusive scan helper ----
__device__ inline int block_excl_scan(int v, int* lds, int nw) {
    int lane = threadIdx.x & 63;
    int wid = (int)(threadIdx.x >> 6);
    int x = v;
    #pragma unroll
    for (int off = 1; off < 64; off <<= 1) {
        int y = __shfl_up(x, off);
        if (lane >= off) x += y;
    }
    if (lane == 63) lds[wid] = x;
    __syncthreads();
    if (wid == 0) {
        int s = (lane < nw) ? lds[lane] : 0;
        #pragma unroll
        for (int off = 1; off < 16; off <<= 1) {
            int y = __shfl_up(s, off);
            if (lane >= off) s += y;
        }
        if (lane < nw) lds[lane] = s;
    }
    __syncthreads();
    int waveoff = (wid == 0) ? 0 : lds[wid - 1];
    return waveoff + x - v;
}

// Fused prologue: [0,PBLK) = p1 histogram; [PBLK,+INIT_BLKS) = bf16 table init;
// rest = zero flags + selflag. All independent.
__global__ void k_prologue(const int* __restrict__ row, int* __restrict__ mat,
                           const float4* __restrict__ u4, const float4* __restrict__ i4,
                           uint4* __restrict__ cur,
                           int* __restrict__ flags, int* __restrict__ selflag) {
    __shared__ int h[NBKT];
    int blk = blockIdx.x;
    if (blk < PBLK) {
        for (int i = threadIdx.x; i < NBKT; i += 256) h[i] = 0;
        __syncthreads();
        int beg = blk * EPB, end = beg + EPB;
        for (int e = beg + threadIdx.x; e < end; e += 256)
            atomicAdd(&h[row[e] >> 8], 1);
        __syncthreads();
        int mb = mcol(blk);
        for (int i = threadIdx.x; i < NBKT; i += 256)
            mat[i * PBLK + mb] = h[i];
    } else if (blk < PBLK + INIT_BLKS) {
        size_t total8 = (size_t)NNODES * D / 8;
        size_t ub8 = (size_t)NUSERS * D / 8;
        size_t stride = (size_t)INIT_BLKS * 256;
        for (size_t i = (size_t)(blk - PBLK) * 256 + threadIdx.x; i < total8; i += stride) {
            const float4* src = (i < ub8) ? &u4[2 * i] : &i4[2 * (i - ub8)];
            float4 a = src[0], b = src[1];
            uint4 o;
            o.x = (bf16_rne(a.y) << 16) | bf16_rne(a.x);
            o.y = (bf16_rne(a.w) << 16) | bf16_rne(a.z);
            o.z = (bf16_rne(b.y) << 16) | bf16_rne(b.x);
            o.w = (bf16_rne(b.w) << 16) | bf16_rne(b.z);
            cur[i] = o;
        }
    } else {
        int i = (blk - PBLK - INIT_BLKS) * 256 + threadIdx.x;
        if (i < NNODES) { flags[i] = 0; selflag[i] = 0; }
    }
}

__global__ void k_blocksum(const int* __restrict__ src, int* __restrict__ bsums, int n) {
    int i = blockIdx.x * 256 + threadIdx.x;
    int v = (i < n) ? src[i] : 0;
    #pragma unroll
    for (int off = 32; off; off >>= 1) v += __shfl_down(v, off);
    __shared__ int lds[4];
    int lane = threadIdx.x & 63, wid = (int)(threadIdx.x >> 6);
    if (lane == 0) lds[wid] = v;
    __syncthreads();
    if (threadIdx.x == 0) bsums[blockIdx.x] = lds[0] + lds[1] + lds[2] + lds[3];
}

// merged scan (+ extra blocks set selflag/flags for selected nodes)
__global__ void k_scan2(int* __restrict__ mat, const int* __restrict__ bsums, int n,
                        const int* __restrict__ users, const int* __restrict__ items,
                        int* __restrict__ selflag, int* __restrict__ flags) {
    int b = blockIdx.x;
    if (b >= MB) {
        int idx = (b - MB) * 256 + threadIdx.x;
        if (idx < 2 * NSEL) {
            int node = (idx < NSEL) ? users[idx] : NUSERS + items[idx - NSEL];
            selflag[node] = 1;
            flags[node] = 1;
        }
        return;
    }
    __shared__ int red[4];
    __shared__ int lds[4];
    int lane = threadIdx.x & 63, wid = (int)(threadIdx.x >> 6);
    int s = 0;
    for (int j = threadIdx.x; j < b; j += 256) s += bsums[j];
    #pragma unroll
    for (int off = 32; off; off >>= 1) s += __shfl_down(s, off);
    if (lane == 0) red[wid] = s;
    __syncthreads();
    int base = red[0] + red[1] + red[2] + red[3];
    int i = b * 256 + threadIdx.x;
    int v = (i < n) ? mat[i] : 0;
    int ex = block_excl_scan(v, lds, 4);
    if (i < n) mat[i] = base + ex;
}

// P2: partition scatter; tmp.x = row-in-bucket, tmp.y = packed (val14<<18)|col18.
// Single 8B store per edge; same-XCD-adjacent segments via mcol.
__global__ void k_p2(const int* __restrict__ row, const int* __restrict__ col,
                     const float* __restrict__ val, const int* __restrict__ mat,
                     int2* __restrict__ tmp) {
    __shared__ int cur[NBKT];
    int mb = mcol(blockIdx.x);
    for (int i = threadIdx.x; i < NBKT; i += 256)
        cur[i] = mat[i * PBLK + mb];
    __syncthreads();
    int beg = blockIdx.x * EPB, end = beg + EPB;
    for (int e = beg + threadIdx.x; e < end; e += 256) {
        int r = row[e];
        int b = r >> 8;
        int pos = atomicAdd(&cur[b], 1);
        int q = (int)(val[e] * 16384.f + 0.5f);
        if (q > 16383) q = 16383;
        int2 rc;
        rc.x = r & 255;
        rc.y = (int)(((uint_t)q << 18) | (uint_t)col[e]);
        tmp[pos] = rc;
    }
}

// P3: per-bucket exact CSR via LDS staging; writes packed 4B recs (val14|col18)
// + fused mark: for records of selected rows, set flags[col]=1
__global__ void k_p3(const int2* __restrict__ tmp, const int* __restrict__ mat,
                     uint_t* __restrict__ recs, int* __restrict__ row_start,
                     const int* __restrict__ selflag, int* __restrict__ flags) {
    __shared__ int2 buf[BCAP];        // 64 KB
    __shared__ int h[256];
    __shared__ int lds[4];
    __shared__ unsigned char selb[256];
    int b = blockIdx.x;
    int beg = mat[b * PBLK];
    int end = (b + 1 < NBKT) ? mat[(b + 1) * PBLK] : NEDGES;
    int n = end - beg;
    int rowid = b * 256 + threadIdx.x;
    h[threadIdx.x] = 0;
    selb[threadIdx.x] = (rowid < NNODES) ? (unsigned char)selflag[rowid] : 0;
    if (n <= BCAP) {
        for (int i = threadIdx.x; i < n; i += 256) buf[i] = tmp[beg + i];
        __syncthreads();
        for (int i = threadIdx.x; i < n; i += 256)
            atomicAdd(&h[buf[i].x], 1);
        __syncthreads();
        int ex = block_excl_scan(h[threadIdx.x], lds, 4);
        if (rowid < NNODES) row_start[rowid] = beg + ex;
        if (b == NBKT - 1 && threadIdx.x == 0) row_start[NNODES] = NEDGES;
        h[threadIdx.x] = ex;
        __syncthreads();
        for (int i = threadIdx.x; i < n; i += 256) {
            int2 rc = buf[i];
            int r = rc.x;
            int pos = beg + atomicAdd(&h[r], 1);
            recs[pos] = (uint_t)rc.y;
            if (selb[r]) flags[(uint_t)rc.y & COLMASK] = 1;
        }
    } else {
        __syncthreads();
        for (int e = beg + threadIdx.x; e < end; e += 256)
            atomicAdd(&h[tmp[e].x], 1);
        __syncthreads();
        int ex = block_excl_scan(h[threadIdx.x], lds, 4);
        if (rowid < NNODES) row_start[rowid] = beg + ex;
        if (b == NBKT - 1 && threadIdx.x == 0) row_start[NNODES] = NEDGES;
        h[threadIdx.x] = ex;
        __syncthreads();
        for (int e = beg + threadIdx.x; e < end; e += 256) {
            int2 rc = tmp[e];
            int r = rc.x;
            int pos = beg + atomicAdd(&h[r], 1);
            recs[pos] = (uint_t)rc.y;
            if (selb[r]) flags[(uint_t)rc.y & COLMASK] = 1;
        }
    }
}

// CSR SpMM on bf16 table: one wave per row, register accumulation, single
// non-atomic write. XCD-chunked row swizzle + 8-deep gather unroll.
__global__ void k_spmm_csr(const uint_t* __restrict__ emb, uint_t* __restrict__ outp,
                           const int* __restrict__ row_start,
                           const uint_t* __restrict__ recs,
                           const int* __restrict__ flags, int use_flags) {
    int lane = threadIdx.x & 63;
    int blk = swz_blk((int)blockIdx.x, (int)gridDim.x);
    int w = blk * 4 + (int)(threadIdx.x >> 6);
    if (w >= NNODES) return;
    if (use_flags && __builtin_amdgcn_readfirstlane(flags[w]) == 0) return;
    int beg = __builtin_amdgcn_readfirstlane(row_start[w]);
    int end = __builtin_amdgcn_readfirstlane(row_start[w + 1]);
    float ax = 0.f, ay = 0.f;
    int e = beg;
    for (; e + 7 < end; e += 8) {
        uint_t q0 = recs[e],     q1 = recs[e + 1], q2 = recs[e + 2], q3 = recs[e + 3];
        uint_t q4 = recs[e + 4], q5 = recs[e + 5], q6 = recs[e + 6], q7 = recs[e + 7];
        uint_t g0 = emb[(size_t)(q0 & COLMASK) * 64 + lane];
        uint_t g1 = emb[(size_t)(q1 & COLMASK) * 64 + lane];
        uint_t g2 = emb[(size_t)(q2 & COLMASK) * 64 + lane];
        uint_t g3 = emb[(size_t)(q3 & COLMASK) * 64 + lane];
        uint_t g4 = emb[(size_t)(q4 & COLMASK) * 64 + lane];
        uint_t g5 = emb[(size_t)(q5 & COLMASK) * 64 + lane];
        uint_t g6 = emb[(size_t)(q6 & COLMASK) * 64 + lane];
        uint_t g7 = emb[(size_t)(q7 & COLMASK) * 64 + lane];
        float v0 = (float)(q0 >> 18), v1 = (float)(q1 >> 18);
        float v2 = (float)(q2 >> 18), v3 = (float)(q3 >> 18);
        float v4 = (float)(q4 >> 18), v5 = (float)(q5 >> 18);
        float v6 = (float)(q6 >> 18), v7 = (float)(q7 >> 18);
        ax += v0 * __uint_as_float(g0 << 16) + v1 * __uint_as_float(g1 << 16)
            + v2 * __uint_as_float(g2 << 16) + v3 * __uint_as_float(g3 << 16)
            + v4 * __uint_as_float(g4 << 16) + v5 * __uint_as_float(g5 << 16)
            + v6 * __uint_as_float(g6 << 16) + v7 * __uint_as_float(g7 << 16);
        ay += v0 * __uint_as_float(g0 & 0xFFFF0000u) + v1 * __uint_as_float(g1 & 0xFFFF0000u)
            + v2 * __uint_as_float(g2 & 0xFFFF0000u) + v3 * __uint_as_float(g3 & 0xFFFF0000u)
            + v4 * __uint_as_float(g4 & 0xFFFF0000u) + v5 * __uint_as_float(g5 & 0xFFFF0000u)
            + v6 * __uint_as_float(g6 & 0xFFFF0000u) + v7 * __uint_as_float(g7 & 0xFFFF0000u);
    }
    for (; e + 3 < end; e += 4) {
        uint_t q0 = recs[e], q1 = recs[e + 1], q2 = recs[e + 2], q3 = recs[e + 3];
        uint_t g0 = emb[(size_t)(q0 & COLMASK) * 64 + lane];
        uint_t g1 = emb[(size_t)(q1 & COLMASK) * 64 + lane];
        uint_t g2 = emb[(size_t)(q2 & COLMASK) * 64 + lane];
        uint_t g3 = emb[(size_t)(q3 & COLMASK) * 64 + lane];
        float v0 = (float)(q0 >> 18), v1 = (float)(q1 >> 18);
        float v2 = (float)(q2 >> 18), v3 = (float)(q3 >> 18);
        ax += v0 * __uint_as_float(g0 << 16) + v1 * __uint_as_float(g1 << 16)
            + v2 * __uint_as_float(g2 << 16) + v3 * __uint_as_float(g3 << 16);
        ay += v0 * __uint_as_float(g0 & 0xFFFF0000u) + v1 * __uint_as_float(g1 & 0xFFFF0000u)
            + v2 * __uint_as_float(g2 & 0xFFFF0000u) + v3 * __uint_as_float(g3 & 0xFFFF0000u);
    }
    for (; e < end; ++e) {
        uint_t q = recs[e];
        float v = (float)(q >> 18);
        uint_t g = emb[(size_t)(q & COLMASK) * 64 + lane];
        ax += v * __uint_as_float(g << 16);
        ay += v * __uint_as_float(g & 0xFFFF0000u);
    }
    ax *= (1.f / 16384.f);
    ay *= (1.f / 16384.f);
    outp[(size_t)w * 64 + lane] = (bf16_rne(ay) << 16) | bf16_rne(ax);
}

// Final fused kernel: per selected slot compute e0+e1+e2+l3, then paired dot.
// Block b: waves 0,1 = user slots 2b,2b+1; waves 2,3 = item slots 2b,2b+1.
__global__ void k_final(const uint_t* __restrict__ embA,      // e2 table (bufA)
                        const uint_t* __restrict__ embB,      // e1 table (bufB)
                        const float* __restrict__ user_emb,
                        const float* __restrict__ item_emb,
                        const int* __restrict__ users, const int* __restrict__ items,
                        const int* __restrict__ row_start, const uint_t* __restrict__ recs,
                        float* __restrict__ out) {
    __shared__ float ush[2][64][2];
    int lane = threadIdx.x & 63;
    int wid = (int)(threadIdx.x >> 6);        // 0..3
    int pairIdx = blockIdx.x * 2 + (wid & 1); // output index
    int isItem = wid >> 1;
    int node, idx0;
    const float* e0p;
    if (isItem) {
        idx0 = items[pairIdx];
        node = NUSERS + idx0;
        e0p = &item_emb[(size_t)idx0 * D];
    } else {
        idx0 = users[pairIdx];
        node = idx0;
        e0p = &user_emb[(size_t)idx0 * D];
    }
    const float2 e0 = *(const float2*)(&e0p[lane * 2]);
    uint_t u1 = embB[(size_t)node * 64 + lane];
    uint_t u2 = embA[(size_t)node * 64 + lane];
    float ax = e0.x + __uint_as_float(u1 << 16) + __uint_as_float(u2 << 16);
    float ay = e0.y + __uint_as_float(u1 & 0xFFFF0000u) + __uint_as_float(u2 & 0xFFFF0000u);
    int beg = __builtin_amdgcn_readfirstlane(row_start[node]);
    int end = __builtin_amdgcn_readfirstlane(row_start[node + 1]);
    for (int e = beg; e < end; ++e) {
        uint_t q = recs[e];
        float v = (float)(q >> 18) * (1.f / 16384.f);
        uint_t g = embA[(size_t)(q & COLMASK) * 64 + lane];
        ax += v * __uint_as_float(g << 16);
        ay += v * __uint_as_float(g & 0xFFFF0000u);
    }
    if (!isItem) { ush[wid][lane][0] = ax; ush[wid][lane][1] = ay; }
    __syncthreads();
    if (isItem) {
        float s = ush[wid - 2][lane][0] * ax + ush[wid - 2][lane][1] * ay;
        #pragma unroll
        for (int off = 32; off; off >>= 1) s += __shfl_down(s, off);
        if (lane == 0) out[pairIdx] = s * (1.0f / 16.0f);
    }
}

extern "C" void kernel_launch(void* const* d_in, const int* in_sizes, int n_in,
                              void* d_out, int out_size, void* d_ws, size_t ws_size,
                              hipStream_t stream) {
    const float* user_emb = (const float*)d_in[0];
    const float* item_emb = (const float*)d_in[1];
    const float* edge_val = (const float*)d_in[2];
    const int*   edge_row = (const int*)d_in[3];
    const int*   edge_col = (const int*)d_in[4];
    const int*   users    = (const int*)d_in[5];
    const int*   items    = (const int*)d_in[6];
    float* out = (float*)d_out;

    const size_t tab = (size_t)NNODES * D;                   // elements
    ushort_t* bufA   = (ushort_t*)d_ws;                      // 38.4 MB bf16
    ushort_t* bufB   = bufA + tab;                           // 38.4 MB bf16
    uint_t* recs     = (uint_t*)(bufB + tab);                // 12.8 MB packed
    int2*  tmp       = (int2*)(recs + NEDGES);               // 25.6 MB
    int*   mat       = (int*)(tmp + NEDGES);                 // 2.4 MB
    int*   row_start = mat + MATN;                           // 600 KB
    int*   flags     = row_start + NNODES + 1;               // 600 KB
    int*   selflag   = flags + NNODES;                       // 600 KB
    int*   bsums     = selflag + NNODES;                     // 9.4 KB

    // ---- prologue: p1 histogram + bf16 init + zero flags/selflag ----
    k_prologue<<<PBLK + INIT_BLKS + FLG_BLKS, 256, 0, stream>>>(
        edge_row, mat, (const float4*)user_emb, (const float4*)item_emb,
        (uint4*)bufA, flags, selflag);

    // ---- CSR build ----
    k_blocksum<<<MB, 256, 0, stream>>>(mat, bsums, MATN);
    k_scan2<<<MB + SELSET_BLKS, 256, 0, stream>>>(mat, bsums, MATN,
                                                  users, items, selflag, flags);
    k_p2<<<PBLK, 256, 0, stream>>>(edge_row, edge_col, edge_val, mat, tmp);
    k_p3<<<NBKT, 256, 0, stream>>>(tmp, mat, recs, row_start, selflag, flags);

    // layer 1: full
    k_spmm_csr<<<(NNODES + 3) / 4, 256, 0, stream>>>((const uint_t*)bufA, (uint_t*)bufB,
                                                     row_start, recs, flags, 0);
    // layer 2: only rows consumed downstream (~47%)
    k_spmm_csr<<<(NNODES + 3) / 4, 256, 0, stream>>>((const uint_t*)bufB, (uint_t*)bufA,
                                                     row_start, recs, flags, 1);
    // final: e0+e1+e2+layer3 at selected slots + paired dot
    k_final<<<NSEL / 2, 256, 0, stream>>>((const uint_t*)bufA, (const uint_t*)bufB,
                                          user_emb, item_emb, users, items,
                                          row_start, recs, out);
}

// Round 13
// 267.760 us; speedup vs baseline: 1.2481x; 1.0583x over previous
//
#include <hip/hip_runtime.h>

#define D 128
#define NUSERS 100000
#define NITEMS 50000
#define NNODES 150000
#define NEDGES 3200000
#define NSEL 2048
#define NBKT 586                 // ceil(150000 / 256) row-buckets of 256 rows
#define PBLK 1000                // partition blocks; EPB divisible by 1024
#define EPB (NEDGES / PBLK)      // 3200 edges per partition block
#define MATN (NBKT * PBLK)       // 586000 (bucket-major count matrix)
#define MB ((MATN + 255) / 256)  // 2290 scan blocks
#define BCAP 8192                // LDS bucket capacity in k_p3 (records)
#define INIT_BLKS 2048
#define FLG_BLKS ((NNODES + 255) / 256)   // 586
#define SELSET_BLKS ((2 * NSEL + 255) / 256)  // 16
#define COLMASK 0x3FFFFu

typedef unsigned int uint_t;
typedef unsigned short ushort_t;
typedef unsigned char uchar_t;

__device__ inline uint_t bf16_rne(float f) {
    uint_t x = __float_as_uint(f);
    return (x + 0x7FFFu + ((x >> 16) & 1u)) >> 16;
}

// same-XCD-adjacent column permutation for mat/tmp segments (PBLK=1000, 8 XCDs)
__device__ inline int mcol(int b) { return (b & 7) * 125 + (b >> 3); }

// bijective XCD-chunked block swizzle (m204 variant; works for any n)
__device__ inline int swz_blk(int b, int n) {
    int q = n >> 3, r = n & 7;
    int x = b & 7, i = b >> 3;
    return (x < r) ? x * (q + 1) + i : r * (q + 1) + (x - r) * q + i;
}

// ---- generic block exclusive scan helper ----
__device__ inline int block_excl_scan(int v, int* lds, int nw) {
    int lane = threadIdx.x & 63;
    int wid = (int)(threadIdx.x >> 6);
    int x = v;
    #pragma unroll
    for (int off = 1; off < 64; off <<= 1) {
        int y = __shfl_up(x, off);
        if (lane >= off) x += y;
    }
    if (lane == 63) lds[wid] = x;
    __syncthreads();
    if (wid == 0) {
        int s = (lane < nw) ? lds[lane] : 0;
        #pragma unroll
        for (int off = 1; off < 16; off <<= 1) {
            int y = __shfl_up(s, off);
            if (lane >= off) s += y;
        }
        if (lane < nw) lds[lane] = s;
    }
    __syncthreads();
    int waveoff = (wid == 0) ? 0 : lds[wid - 1];
    return waveoff + x - v;
}

// Fused prologue: [0,PBLK) = p1 histogram; [PBLK,+INIT_BLKS) = bf16 table init;
// rest = zero flags + selflag. All independent.
__global__ void k_prologue(const int* __restrict__ row, int* __restrict__ mat,
                           const float4* __restrict__ u4, const float4* __restrict__ i4,
                           uint4* __restrict__ cur,
                           int* __restrict__ flags, int* __restrict__ selflag) {
    __shared__ int h[NBKT];
    int blk = blockIdx.x;
    if (blk < PBLK) {
        for (int i = threadIdx.x; i < NBKT; i += 256) h[i] = 0;
        __syncthreads();
        int beg = blk * EPB, end = beg + EPB;
        for (int e = beg + (int)threadIdx.x * 4; e + 3 < end; e += 1024) {
            int4 r4 = *(const int4*)&row[e];
            atomicAdd(&h[r4.x >> 8], 1);
            atomicAdd(&h[r4.y >> 8], 1);
            atomicAdd(&h[r4.z >> 8], 1);
            atomicAdd(&h[r4.w >> 8], 1);
        }
        __syncthreads();
        int mb = mcol(blk);
        for (int i = threadIdx.x; i < NBKT; i += 256)
            mat[i * PBLK + mb] = h[i];
    } else if (blk < PBLK + INIT_BLKS) {
        size_t total8 = (size_t)NNODES * D / 8;
        size_t ub8 = (size_t)NUSERS * D / 8;
        size_t stride = (size_t)INIT_BLKS * 256;
        for (size_t i = (size_t)(blk - PBLK) * 256 + threadIdx.x; i < total8; i += stride) {
            const float4* src = (i < ub8) ? &u4[2 * i] : &i4[2 * (i - ub8)];
            float4 a = src[0], b = src[1];
            uint4 o;
            o.x = (bf16_rne(a.y) << 16) | bf16_rne(a.x);
            o.y = (bf16_rne(a.w) << 16) | bf16_rne(a.z);
            o.z = (bf16_rne(b.y) << 16) | bf16_rne(b.x);
            o.w = (bf16_rne(b.w) << 16) | bf16_rne(b.z);
            cur[i] = o;
        }
    } else {
        int i = (blk - PBLK - INIT_BLKS) * 256 + threadIdx.x;
        if (i < NNODES) { flags[i] = 0; selflag[i] = 0; }
    }
}

__global__ void k_blocksum(const int* __restrict__ src, int* __restrict__ bsums, int n) {
    int i = blockIdx.x * 256 + threadIdx.x;
    int v = (i < n) ? src[i] : 0;
    #pragma unroll
    for (int off = 32; off; off >>= 1) v += __shfl_down(v, off);
    __shared__ int lds[4];
    int lane = threadIdx.x & 63, wid = (int)(threadIdx.x >> 6);
    if (lane == 0) lds[wid] = v;
    __syncthreads();
    if (threadIdx.x == 0) bsums[blockIdx.x] = lds[0] + lds[1] + lds[2] + lds[3];
}

// merged scan (+ extra blocks set selflag/flags for selected nodes)
__global__ void k_scan2(int* __restrict__ mat, const int* __restrict__ bsums, int n,
                        const int* __restrict__ users, const int* __restrict__ items,
                        int* __restrict__ selflag, int* __restrict__ flags) {
    int b = blockIdx.x;
    if (b >= MB) {
        int idx = (b - MB) * 256 + threadIdx.x;
        if (idx < 2 * NSEL) {
            int node = (idx < NSEL) ? users[idx] : NUSERS + items[idx - NSEL];
            selflag[node] = 1;
            flags[node] = 1;
        }
        return;
    }
    __shared__ int red[4];
    __shared__ int lds[4];
    int lane = threadIdx.x & 63, wid = (int)(threadIdx.x >> 6);
    int s = 0;
    for (int j = threadIdx.x; j < b; j += 256) s += bsums[j];
    #pragma unroll
    for (int off = 32; off; off >>= 1) s += __shfl_down(s, off);
    if (lane == 0) red[wid] = s;
    __syncthreads();
    int base = red[0] + red[1] + red[2] + red[3];
    int i = b * 256 + threadIdx.x;
    int v = (i < n) ? mat[i] : 0;
    int ex = block_excl_scan(v, lds, 4);
    if (i < n) mat[i] = base + ex;
}

// P2: partition scatter; t32 = (val14<<18)|col18, t8 = row-in-bucket.
// int4/float4 vectorized edge reads; same-XCD-adjacent segments via mcol.
__global__ void k_p2(const int* __restrict__ row, const int* __restrict__ col,
                     const float* __restrict__ val, const int* __restrict__ mat,
                     uint_t* __restrict__ t32, uchar_t* __restrict__ t8) {
    __shared__ int cur[NBKT];
    int mb = mcol(blockIdx.x);
    for (int i = threadIdx.x; i < NBKT; i += 256)
        cur[i] = mat[i * PBLK + mb];
    __syncthreads();
    int beg = blockIdx.x * EPB, end = beg + EPB;
    for (int e = beg + (int)threadIdx.x * 4; e + 3 < end; e += 1024) {
        int4 r4 = *(const int4*)&row[e];
        int4 c4 = *(const int4*)&col[e];
        float4 v4 = *(const float4*)&val[e];
        #pragma unroll
        for (int k = 0; k < 4; ++k) {
            int r = (k == 0) ? r4.x : (k == 1) ? r4.y : (k == 2) ? r4.z : r4.w;
            int c = (k == 0) ? c4.x : (k == 1) ? c4.y : (k == 2) ? c4.z : c4.w;
            float v = (k == 0) ? v4.x : (k == 1) ? v4.y : (k == 2) ? v4.z : v4.w;
            int b = r >> 8;
            int pos = atomicAdd(&cur[b], 1);
            int q = (int)(v * 16384.f + 0.5f);
            if (q > 16383) q = 16383;
            t32[pos] = ((uint_t)q << 18) | (uint_t)c;
            t8[pos] = (uchar_t)(r & 255);
        }
    }
}

// P3: per-bucket exact CSR via LDS staging (40KB); writes packed 4B recs
// + fused mark: for records of selected rows, set flags[col]=1
__global__ void k_p3(const uint_t* __restrict__ t32, const uchar_t* __restrict__ t8,
                     const int* __restrict__ mat, uint_t* __restrict__ recs,
                     int* __restrict__ row_start,
                     const int* __restrict__ selflag, int* __restrict__ flags) {
    __shared__ uint_t b32[BCAP];      // 32 KB
    __shared__ uchar_t b8[BCAP];      // 8 KB
    __shared__ int h[256];
    __shared__ int lds[4];
    __shared__ unsigned char selb[256];
    int b = blockIdx.x;
    int beg = mat[b * PBLK];
    int end = (b + 1 < NBKT) ? mat[(b + 1) * PBLK] : NEDGES;
    int n = end - beg;
    int rowid = b * 256 + threadIdx.x;
    h[threadIdx.x] = 0;
    selb[threadIdx.x] = (rowid < NNODES) ? (unsigned char)selflag[rowid] : 0;
    if (n <= BCAP) {
        for (int i = threadIdx.x; i < n; i += 256) {
            b32[i] = t32[beg + i];
            b8[i] = t8[beg + i];
        }
        __syncthreads();
        for (int i = threadIdx.x; i < n; i += 256)
            atomicAdd(&h[b8[i]], 1);
        __syncthreads();
        int ex = block_excl_scan(h[threadIdx.x], lds, 4);
        if (rowid < NNODES) row_start[rowid] = beg + ex;
        if (b == NBKT - 1 && threadIdx.x == 0) row_start[NNODES] = NEDGES;
        h[threadIdx.x] = ex;
        __syncthreads();
        for (int i = threadIdx.x; i < n; i += 256) {
            int r = b8[i];
            uint_t rec = b32[i];
            int pos = beg + atomicAdd(&h[r], 1);
            recs[pos] = rec;
            if (selb[r]) flags[rec & COLMASK] = 1;
        }
    } else {
        __syncthreads();
        for (int e = beg + threadIdx.x; e < end; e += 256)
            atomicAdd(&h[t8[e]], 1);
        __syncthreads();
        int ex = block_excl_scan(h[threadIdx.x], lds, 4);
        if (rowid < NNODES) row_start[rowid] = beg + ex;
        if (b == NBKT - 1 && threadIdx.x == 0) row_start[NNODES] = NEDGES;
        h[threadIdx.x] = ex;
        __syncthreads();
        for (int e = beg + threadIdx.x; e < end; e += 256) {
            int r = t8[e];
            uint_t rec = t32[e];
            int pos = beg + atomicAdd(&h[r], 1);
            recs[pos] = rec;
            if (selb[r]) flags[rec & COLMASK] = 1;
        }
    }
}

// CSR SpMM on bf16 table: one wave per row, register accumulation, single
// non-atomic write. XCD-chunked row swizzle + 8-deep gather unroll.
__global__ void k_spmm_csr(const uint_t* __restrict__ emb, uint_t* __restrict__ outp,
                           const int* __restrict__ row_start,
                           const uint_t* __restrict__ recs,
                           const int* __restrict__ flags, int use_flags) {
    int lane = threadIdx.x & 63;
    int blk = swz_blk((int)blockIdx.x, (int)gridDim.x);
    int w = blk * 4 + (int)(threadIdx.x >> 6);
    if (w >= NNODES) return;
    if (use_flags && __builtin_amdgcn_readfirstlane(flags[w]) == 0) return;
    int beg = __builtin_amdgcn_readfirstlane(row_start[w]);
    int end = __builtin_amdgcn_readfirstlane(row_start[w + 1]);
    float ax = 0.f, ay = 0.f;
    int e = beg;
    for (; e + 7 < end; e += 8) {
        uint_t q0 = recs[e],     q1 = recs[e + 1], q2 = recs[e + 2], q3 = recs[e + 3];
        uint_t q4 = recs[e + 4], q5 = recs[e + 5], q6 = recs[e + 6], q7 = recs[e + 7];
        uint_t g0 = emb[(size_t)(q0 & COLMASK) * 64 + lane];
        uint_t g1 = emb[(size_t)(q1 & COLMASK) * 64 + lane];
        uint_t g2 = emb[(size_t)(q2 & COLMASK) * 64 + lane];
        uint_t g3 = emb[(size_t)(q3 & COLMASK) * 64 + lane];
        uint_t g4 = emb[(size_t)(q4 & COLMASK) * 64 + lane];
        uint_t g5 = emb[(size_t)(q5 & COLMASK) * 64 + lane];
        uint_t g6 = emb[(size_t)(q6 & COLMASK) * 64 + lane];
        uint_t g7 = emb[(size_t)(q7 & COLMASK) * 64 + lane];
        float v0 = (float)(q0 >> 18), v1 = (float)(q1 >> 18);
        float v2 = (float)(q2 >> 18), v3 = (float)(q3 >> 18);
        float v4 = (float)(q4 >> 18), v5 = (float)(q5 >> 18);
        float v6 = (float)(q6 >> 18), v7 = (float)(q7 >> 18);
        ax += v0 * __uint_as_float(g0 << 16) + v1 * __uint_as_float(g1 << 16)
            + v2 * __uint_as_float(g2 << 16) + v3 * __uint_as_float(g3 << 16)
            + v4 * __uint_as_float(g4 << 16) + v5 * __uint_as_float(g5 << 16)
            + v6 * __uint_as_float(g6 << 16) + v7 * __uint_as_float(g7 << 16);
        ay += v0 * __uint_as_float(g0 & 0xFFFF0000u) + v1 * __uint_as_float(g1 & 0xFFFF0000u)
            + v2 * __uint_as_float(g2 & 0xFFFF0000u) + v3 * __uint_as_float(g3 & 0xFFFF0000u)
            + v4 * __uint_as_float(g4 & 0xFFFF0000u) + v5 * __uint_as_float(g5 & 0xFFFF0000u)
            + v6 * __uint_as_float(g6 & 0xFFFF0000u) + v7 * __uint_as_float(g7 & 0xFFFF0000u);
    }
    for (; e + 3 < end; e += 4) {
        uint_t q0 = recs[e], q1 = recs[e + 1], q2 = recs[e + 2], q3 = recs[e + 3];
        uint_t g0 = emb[(size_t)(q0 & COLMASK) * 64 + lane];
        uint_t g1 = emb[(size_t)(q1 & COLMASK) * 64 + lane];
        uint_t g2 = emb[(size_t)(q2 & COLMASK) * 64 + lane];
        uint_t g3 = emb[(size_t)(q3 & COLMASK) * 64 + lane];
        float v0 = (float)(q0 >> 18), v1 = (float)(q1 >> 18);
        float v2 = (float)(q2 >> 18), v3 = (float)(q3 >> 18);
        ax += v0 * __uint_as_float(g0 << 16) + v1 * __uint_as_float(g1 << 16)
            + v2 * __uint_as_float(g2 << 16) + v3 * __uint_as_float(g3 << 16);
        ay += v0 * __uint_as_float(g0 & 0xFFFF0000u) + v1 * __uint_as_float(g1 & 0xFFFF0000u)
            + v2 * __uint_as_float(g2 & 0xFFFF0000u) + v3 * __uint_as_float(g3 & 0xFFFF0000u);
    }
    for (; e < end; ++e) {
        uint_t q = recs[e];
        float v = (float)(q >> 18);
        uint_t g = emb[(size_t)(q & COLMASK) * 64 + lane];
        ax += v * __uint_as_float(g << 16);
        ay += v * __uint_as_float(g & 0xFFFF0000u);
    }
    ax *= (1.f / 16384.f);
    ay *= (1.f / 16384.f);
    outp[(size_t)w * 64 + lane] = (bf16_rne(ay) << 16) | bf16_rne(ax);
}

// Final fused kernel: per selected slot compute e0+e1+e2+l3, then paired dot.
// Block b: waves 0,1 = user slots 2b,2b+1; waves 2,3 = item slots 2b,2b+1.
__global__ void k_final(const uint_t* __restrict__ embA,      // e2 table (bufA)
                        const uint_t* __restrict__ embB,      // e1 table (bufB)
                        const float* __restrict__ user_emb,
                        const float* __restrict__ item_emb,
                        const int* __restrict__ users, const int* __restrict__ items,
                        const int* __restrict__ row_start, const uint_t* __restrict__ recs,
                        float* __restrict__ out) {
    __shared__ float ush[2][64][2];
    int lane = threadIdx.x & 63;
    int wid = (int)(threadIdx.x >> 6);        // 0..3
    int pairIdx = blockIdx.x * 2 + (wid & 1); // output index
    int isItem = wid >> 1;
    int node, idx0;
    const float* e0p;
    if (isItem) {
        idx0 = items[pairIdx];
        node = NUSERS + idx0;
        e0p = &item_emb[(size_t)idx0 * D];
    } else {
        idx0 = users[pairIdx];
        node = idx0;
        e0p = &user_emb[(size_t)idx0 * D];
    }
    const float2 e0 = *(const float2*)(&e0p[lane * 2]);
    uint_t u1 = embB[(size_t)node * 64 + lane];
    uint_t u2 = embA[(size_t)node * 64 + lane];
    float ax = e0.x + __uint_as_float(u1 << 16) + __uint_as_float(u2 << 16);
    float ay = e0.y + __uint_as_float(u1 & 0xFFFF0000u) + __uint_as_float(u2 & 0xFFFF0000u);
    int beg = __builtin_amdgcn_readfirstlane(row_start[node]);
    int end = __builtin_amdgcn_readfirstlane(row_start[node + 1]);
    for (int e = beg; e < end; ++e) {
        uint_t q = recs[e];
        float v = (float)(q >> 18) * (1.f / 16384.f);
        uint_t g = embA[(size_t)(q & COLMASK) * 64 + lane];
        ax += v * __uint_as_float(g << 16);
        ay += v * __uint_as_float(g & 0xFFFF0000u);
    }
    if (!isItem) { ush[wid][lane][0] = ax; ush[wid][lane][1] = ay; }
    __syncthreads();
    if (isItem) {
        float s = ush[wid - 2][lane][0] * ax + ush[wid - 2][lane][1] * ay;
        #pragma unroll
        for (int off = 32; off; off >>= 1) s += __shfl_down(s, off);
        if (lane == 0) out[pairIdx] = s * (1.0f / 16.0f);
    }
}

extern "C" void kernel_launch(void* const* d_in, const int* in_sizes, int n_in,
                              void* d_out, int out_size, void* d_ws, size_t ws_size,
                              hipStream_t stream) {
    const float* user_emb = (const float*)d_in[0];
    const float* item_emb = (const float*)d_in[1];
    const float* edge_val = (const float*)d_in[2];
    const int*   edge_row = (const int*)d_in[3];
    const int*   edge_col = (const int*)d_in[4];
    const int*   users    = (const int*)d_in[5];
    const int*   items    = (const int*)d_in[6];
    float* out = (float*)d_out;

    const size_t tab = (size_t)NNODES * D;                   // elements
    ushort_t* bufA   = (ushort_t*)d_ws;                      // 38.4 MB bf16
    ushort_t* bufB   = bufA + tab;                           // 38.4 MB bf16
    uint_t* recs     = (uint_t*)(bufB + tab);                // 12.8 MB packed
    uint_t* t32      = recs + NEDGES;                        // 12.8 MB
    uchar_t* t8      = (uchar_t*)(t32 + NEDGES);             // 3.2 MB
    int*   mat       = (int*)(t8 + NEDGES);                  // 2.34 MB
    int*   row_start = mat + MATN;                           // 600 KB
    int*   flags     = row_start + NNODES + 1;               // 600 KB
    int*   selflag   = flags + NNODES;                       // 600 KB
    int*   bsums     = selflag + NNODES;                     // 9.2 KB

    // ---- prologue: p1 histogram + bf16 init + zero flags/selflag ----
    k_prologue<<<PBLK + INIT_BLKS + FLG_BLKS, 256, 0, stream>>>(
        edge_row, mat, (const float4*)user_emb, (const float4*)item_emb,
        (uint4*)bufA, flags, selflag);

    // ---- CSR build ----
    k_blocksum<<<MB, 256, 0, stream>>>(mat, bsums, MATN);
    k_scan2<<<MB + SELSET_BLKS, 256, 0, stream>>>(mat, bsums, MATN,
                                                  users, items, selflag, flags);
    k_p2<<<PBLK, 256, 0, stream>>>(edge_row, edge_col, edge_val, mat, t32, t8);
    k_p3<<<NBKT, 256, 0, stream>>>(t32, t8, mat, recs, row_start, selflag, flags);

    // layer 1: full
    k_spmm_csr<<<(NNODES + 3) / 4, 256, 0, stream>>>((const uint_t*)bufA, (uint_t*)bufB,
                                                     row_start, recs, flags, 0);
    // layer 2: only rows consumed downstream (~47%)
    k_spmm_csr<<<(NNODES + 3) / 4, 256, 0, stream>>>((const uint_t*)bufB, (uint_t*)bufA,
                                                     row_start, recs, flags, 1);
    // final: e0+e1+e2+layer3 at selected slots + paired dot
    k_final<<<NSEL / 2, 256, 0, stream>>>((const uint_t*)bufA, (const uint_t*)bufB,
                                          user_emb, item_emb, users, items,
                                          row_start, recs, out);
}